// Round 6
// baseline (395.885 us; speedup 1.0000x reference)
//
#include <hip/hip_runtime.h>
#include <hip/hip_bf16.h>

// Static problem config (BEVFormer-base-ish, 50x50 BEV grid)
#define L_TOT   19560
#define NQ      2500
#define NCAMS   6
#define M_VAL   (NCAMS * L_TOT)   // 117360

typedef __attribute__((ext_vector_type(8))) short short8;
typedef __attribute__((ext_vector_type(4))) float f32x4;

__device__ __forceinline__ unsigned short f2bf(float x) {
  __hip_bfloat16 h = __float2bfloat16(x);
  return *reinterpret_cast<unsigned short*>(&h);
}
__device__ __forceinline__ unsigned int pack2bf(float lo, float hi) {
  return (unsigned int)f2bf(lo) | ((unsigned int)f2bf(hi) << 16);
}
__device__ __forceinline__ float bf_lo(unsigned int u) {
  return __uint_as_float(u << 16);
}
__device__ __forceinline__ float bf_hi(unsigned int u) {
  return __uint_as_float(u & 0xffff0000u);
}

__device__ __forceinline__ unsigned char canon_bool(const void* in, int i,
                                                    int mode) {
  if (mode == 1) return (unsigned char)(((const unsigned int*)in)[i] != 0u);
  if (mode == 2) return (unsigned char)(((const float*)in)[i] != 0.0f);
  return (unsigned char)(((const unsigned char*)in)[i] != 0);
}

// ---------------------------------------------------------------------------
// Parallel bev_mask canonicalizer (bool may arrive as u8 / i32 / f32).
// ---------------------------------------------------------------------------
__global__ void canon_mask_kernel(const void* __restrict__ in,
                                  unsigned char* __restrict__ outm,
                                  float* __restrict__ invcnt,
                                  const float* __restrict__ b_off,
                                  const float* __restrict__ b_attn,
                                  float* __restrict__ bcat) {
  __shared__ int notI, notF;
  if (threadIdx.x == 0) { notI = 0; notF = 0; }
  __syncthreads();
  const unsigned int* w = (const unsigned int*)in;
  for (int i = threadIdx.x; i < 3750; i += 256) {
    unsigned int x = w[i];
    if (x != 0u && x != 1u)          atomicOr(&notI, 1);
    if (x != 0u && x != 0x3f800000u) atomicOr(&notF, 1);
  }
  __syncthreads();
  const int mode = (notI == 0) ? 1 : ((notF == 0) ? 2 : 0);

  const int i = blockIdx.x * 256 + threadIdx.x;
  if (i < NCAMS * NQ) outm[i] = canon_bool(in, i, mode);

  if (blockIdx.x < 10) {
    const int q0 = blockIdx.x * 250;
    for (int q = q0 + threadIdx.x; q < q0 + 250; q += 256) {
      int cnt = 0;
#pragma unroll
      for (int c = 0; c < NCAMS; ++c) cnt += canon_bool(in, c * NQ + q, mode);
      invcnt[q] = 1.f / (float)max(cnt, 1);
    }
  } else if (blockIdx.x == 10) {
    for (int j = threadIdx.x; j < 768; j += 256)
      bcat[j] = (j < 512) ? b_off[j] : b_attn[j - 512];
  }
}

// ---------------------------------------------------------------------------
// Convert weights to bf16: W_value -> o0[65536]; [W_off;W_attn] -> o1[196608];
// W_out -> o2[65536].
// ---------------------------------------------------------------------------
__global__ void cvt_weights_kernel(const float* __restrict__ wv,
                                   const float* __restrict__ woff,
                                   const float* __restrict__ wattn,
                                   const float* __restrict__ wout,
                                   unsigned short* __restrict__ o0,
                                   unsigned short* __restrict__ o1,
                                   unsigned short* __restrict__ o2) {
  int i = blockIdx.x * 256 + threadIdx.x;
  if (i < 65536)        o0[i] = f2bf(wv[i]);
  else if (i < 196608)  o1[i - 65536] = f2bf(woff[i - 65536]);
  else if (i < 262144)  o1[131072 + (i - 196608)] = f2bf(wattn[i - 196608]);
  else if (i < 327680)  o2[i - 262144] = f2bf(wout[i - 262144]);
}

// ---------------------------------------------------------------------------
// bf16-MFMA GEMM, 64x128 tile, COUNTED-VMCNT RAW BARRIERS + 2-DEEP PIPELINE:
//   C[m, ch] = sum_k bf16(scale[m]*(A[m,k]+A2[m,k])) * W[ch,k] + bias[ch]
//              (+ R[m,ch])
// ROUND-5/6 (round-5 bench was an infra failure — container died twice with
// huge npz-push times; kernel audited: no divergent barriers, static loop
// bounds, guarded loads — not a plausible hang source; resubmitting).
// Round-4 proved occupancy is NOT the lever (28->55% occ moved BW only
// 1.93->2.08 TB/s, traffic clean). The limiter is __syncthreads(): the
// compiler emits s_waitcnt vmcnt(0) before every s_barrier, draining the
// prefetched loads at the NEXT barrier — pipeline depth is effectively 0 and
// every wave convoys on ~700cy of exposed HBM latency 16x per block.
// Fix (guide T4): raw __builtin_amdgcn_s_barrier() with explicit
// lgkmcnt(0)-only fences (LDS visibility), NO vmcnt(0) in the loop; global
// loads stay in flight across barriers, and the compiler's dataflow wait
// before the STORE's use of staging regs becomes a counted vmcnt(4).
// 2-deep ISSUE (A/B named reg sets, kt unrolled x2 -> static indexing): each
// load batch gets a full iteration (both barrier periods + MFMA phases) of
// latency cover. Regs: ~56 arch + 32 agpr = 88 <= 102 cap (256,5). No spill.
// Barrier discipline (single-buffered LDS, 2 barriers/iter):
//  - fence lgkmcnt(0) + barrier BEFORE ds_writes: own ds_reads of the prev
//    tile retired (no read-overwrite race), writers may proceed.
//  - fence lgkmcnt(0) + barrier AFTER ds_writes: writes visible to readers.
// Ledger (round-3 lesson): unified VGPR+AGPR, (arch+agpr)*waves/SIMD <= 512.
// Tripwires: WRITE_SIZE>70MB = spill; absmax>0.0157 = barrier race.
// ---------------------------------------------------------------------------
template <bool BF16_OUT, bool HAS_A2, bool HAS_RES, bool HAS_SCALE>
__global__ __launch_bounds__(256, 5) void gemm_mfma_kernel(
    const float* __restrict__ A, const float* __restrict__ A2,
    const unsigned short* __restrict__ Wbf, const float* __restrict__ bias,
    const float* __restrict__ R, const float* __restrict__ rowscale,
    void* __restrict__ Cv, int M, int N) {
  __shared__ unsigned short As[64 * 40];   // data rows (bf16), pad to 40
  __shared__ unsigned short Bs[128 * 40];  // weight rows (channels)
  const int tid = threadIdx.x;
  const int m0 = blockIdx.x * 64;
  const int n0 = blockIdx.y * 128;
  const int wave = tid >> 6;
  const int lane = tid & 63;
  const int wr = (wave >> 1) * 32;  // row-block within tile (0/32)
  const int wc = (wave & 1) * 64;   // channel-block within tile (0/64)
  const int fr = lane & 15;
  const int fg = lane >> 4;

  // A staging: thread -> (row 0..63, 8-element quarter of the 32-k tile)
  const int sr = tid >> 2;
  const int sc = (tid & 3) * 8;
  const bool a_ok = (m0 + sr) < M;
  const float* Ap = A + (size_t)(m0 + sr) * 256 + sc;
  const float* A2p = HAS_A2 ? (A2 + (size_t)(m0 + sr) * 256 + sc) : nullptr;
  const float ascale = (HAS_SCALE && a_ok) ? rowscale[m0 + sr] : 1.f;
  unsigned short* asw = &As[sr * 40 + sc];

  // B staging: thread -> (channel 0..127, 16-element half of the 32-k tile)
  const int br = tid >> 1;
  const int bc = (tid & 1) * 16;
  const unsigned short* Bp = Wbf + (size_t)(n0 + br) * 256 + bc;
  unsigned short* bsw = &Bs[br * 40 + bc];

  f32x4 acc[4][2] = {};  // [ct(channel)][rt(row)] — 32 AGPR

  // 2-deep register staging: named sets (static indexing, rule #20)
  float4 raA[2], rtA[2], raB[2], rtB[2];
  uint4 rbA0, rbA1, rbB0, rbB1;

#define GEMM_ISSUE(SUF, KT)                                                \
  {                                                                        \
    ra##SUF[0] = a_ok ? *(const float4*)(Ap + (KT) * 32)                   \
                      : make_float4(0.f, 0.f, 0.f, 0.f);                   \
    ra##SUF[1] = a_ok ? *(const float4*)(Ap + (KT) * 32 + 4)               \
                      : make_float4(0.f, 0.f, 0.f, 0.f);                   \
    if (HAS_A2) {                                                          \
      rt##SUF[0] = a_ok ? *(const float4*)(A2p + (KT) * 32)                \
                        : make_float4(0.f, 0.f, 0.f, 0.f);                 \
      rt##SUF[1] = a_ok ? *(const float4*)(A2p + (KT) * 32 + 4)            \
                        : make_float4(0.f, 0.f, 0.f, 0.f);                 \
    }                                                                      \
    rb##SUF##0 = *(const uint4*)(Bp + (KT) * 32);                          \
    rb##SUF##1 = *(const uint4*)(Bp + (KT) * 32 + 8);                      \
  }

// lgkmcnt-only fence + raw barrier: NO vmcnt drain (the whole point).
#define GEMM_FENCE_BARRIER()                                               \
  asm volatile("s_waitcnt lgkmcnt(0)" ::: "memory");                       \
  __builtin_amdgcn_s_barrier();

#define GEMM_BODY(SUF, KT, NEXTKT)                                         \
  {                                                                        \
    GEMM_FENCE_BARRIER(); /* prev tile's ds_reads retired in all waves */  \
    {                                                                      \
      float4 s0 = ra##SUF[0], s1 = ra##SUF[1];                             \
      if (HAS_A2) {                                                        \
        s0.x += rt##SUF[0].x; s0.y += rt##SUF[0].y;                        \
        s0.z += rt##SUF[0].z; s0.w += rt##SUF[0].w;                        \
        s1.x += rt##SUF[1].x; s1.y += rt##SUF[1].y;                        \
        s1.z += rt##SUF[1].z; s1.w += rt##SUF[1].w;                        \
      }                                                                    \
      if (HAS_SCALE) {                                                     \
        s0.x *= ascale; s0.y *= ascale; s0.z *= ascale; s0.w *= ascale;    \
        s1.x *= ascale; s1.y *= ascale; s1.z *= ascale; s1.w *= ascale;    \
      }                                                                    \
      uint4 u0;                                                            \
      u0.x = pack2bf(s0.x, s0.y); u0.y = pack2bf(s0.z, s0.w);              \
      u0.z = pack2bf(s1.x, s1.y); u0.w = pack2bf(s1.z, s1.w);              \
      *(uint4*)asw = u0;                                                   \
      *(uint4*)bsw = rb##SUF##0;                                           \
      *(uint4*)(bsw + 8) = rb##SUF##1;                                     \
    }                                                                      \
    GEMM_FENCE_BARRIER(); /* ds_writes visible to all waves */             \
    if ((NEXTKT) < 8) GEMM_ISSUE(SUF, NEXTKT);                             \
    short8 wf[4], vf[2];                                                   \
    _Pragma("unroll") for (int ct = 0; ct < 4; ++ct)                       \
        wf[ct] = *(const short8*)&Bs[(wc + ct * 16 + fr) * 40 + fg * 8];   \
    _Pragma("unroll") for (int rt2 = 0; rt2 < 2; ++rt2)                    \
        vf[rt2] = *(const short8*)&As[(wr + rt2 * 16 + fr) * 40 + fg * 8]; \
    _Pragma("unroll") for (int ct = 0; ct < 4; ++ct)                       \
        _Pragma("unroll") for (int rt2 = 0; rt2 < 2; ++rt2)                \
            acc[ct][rt2] = __builtin_amdgcn_mfma_f32_16x16x32_bf16(        \
                wf[ct], vf[rt2], acc[ct][rt2], 0, 0, 0);                   \
  }

  GEMM_ISSUE(A, 0);
  GEMM_ISSUE(B, 1);

#pragma unroll
  for (int kt = 0; kt < 8; kt += 2) {
    GEMM_BODY(A, kt, kt + 2);
    GEMM_BODY(B, kt + 1, kt + 3);
  }
#undef GEMM_ISSUE
#undef GEMM_FENCE_BARRIER
#undef GEMM_BODY

  // Epilogue: D layout -> data row = fr, channel = fg*4 + reg
#pragma unroll
  for (int rt2 = 0; rt2 < 2; ++rt2) {
    const int m = m0 + wr + rt2 * 16 + fr;
    if (m >= M) continue;
#pragma unroll
    for (int ct = 0; ct < 4; ++ct) {
      const int ch = n0 + wc + ct * 16 + fg * 4;
      float o[4];
#pragma unroll
      for (int r = 0; r < 4; ++r) o[r] = acc[ct][rt2][r] + bias[ch + r];
      if (HAS_RES) {
        const float4 r4 = *(const float4*)&R[(size_t)m * N + ch];
        o[0] += r4.x; o[1] += r4.y; o[2] += r4.z; o[3] += r4.w;
      }
      if (BF16_OUT) {
        ushort4 u;
        u.x = f2bf(o[0]); u.y = f2bf(o[1]); u.z = f2bf(o[2]); u.w = f2bf(o[3]);
        *(ushort4*)((unsigned short*)Cv + (size_t)m * N + ch) = u;
      } else {
        float4 of; of.x = o[0]; of.y = o[1]; of.z = o[2]; of.w = o[3];
        *(float4*)((float*)Cv + (size_t)m * N + ch) = of;
      }
    }
  }
}

// ---------------------------------------------------------------------------
// Sampler v3: one block per (cam, query) pair; 256 threads = 2 sample-groups
// of 128 threads (2 channels each).
// ---------------------------------------------------------------------------
__global__ __launch_bounds__(256) void sampler3_kernel(
    const unsigned short* __restrict__ v, const float* __restrict__ offlog,
    const float* __restrict__ ref, const unsigned char* __restrict__ mask,
    float* __restrict__ slots) {
  const int pair = blockIdx.x;                 // c * NQ + q
  if (!mask[pair]) return;
  const int c = pair / NQ;
  const int q = pair - c * NQ;
  const int t = threadIdx.x;                   // 0..255

  __shared__ float sx[256], sy[256], sw[256];
  {
    const float Wl[4] = {160.f, 80.f, 40.f, 20.f};
    const float Hl[4] = {92.f, 46.f, 23.f, 12.f};
    const int combo = t;                       // (h,l,p): h=combo>>5
    const int l = (combo >> 3) & 3;
    const int p = combo & 7;
    const int z = p & 3;                       // NP//NZ x NZ reshape
    const float2 rz = ((const float2*)ref)[q * 4 + z];
    const float2 o2 = ((const float2*)offlog)[(size_t)q * 384 + combo];
    sx[combo] = rz.x * Wl[l] + o2.x - 0.5f;
    sy[combo] = rz.y * Hl[l] + o2.y - 0.5f;
    float lg = offlog[(size_t)q * 768 + 512 + combo];
    float mx = lg;
    for (int s = 16; s; s >>= 1) mx = fmaxf(mx, __shfl_xor(mx, s, 32));
    float e = __expf(lg - mx);
    float sm = e;
    for (int s = 16; s; s >>= 1) sm += __shfl_xor(sm, s, 32);
    sw[combo] = e / sm;
  }
  __syncthreads();

  const int WW[4] = {160, 80, 40, 20};
  const int HH[4] = {92, 46, 23, 12};
  const int LS[4] = {0, 14720, 18400, 19320};

  const int tt = t & 127;                      // channel pair
  const int grp = t >> 7;                      // sample group
  const unsigned int* vc =
      (const unsigned int*)(v + (size_t)c * (L_TOT * 256)) + tt;
  const int cbase = (tt >> 4) * 32;
  const int sbase = grp * 16;
  float acc0 = 0.f, acc1 = 0.f;

#pragma unroll
  for (int j = 0; j < 16; ++j) {
    const int s = sbase + j;
    const int lvl = s >> 3;
    const int combo = cbase + s;
    const float x = sx[combo], y = sy[combo], w = sw[combo];
    const float fx0 = floorf(x), fy0 = floorf(y);
    const float fx = x - fx0, fy = y - fy0;
    const int x0 = (int)fx0, y0 = (int)fy0;
    const int Wi = WW[lvl], Hi = HH[lvl];
    const int x0c = min(max(x0, 0), Wi - 1);
    const int x1c = min(max(x0 + 1, 0), Wi - 1);
    const int y0c = min(max(y0, 0), Hi - 1);
    const int y1c = min(max(y0 + 1, 0), Hi - 1);
    const float vx0 = (x0 >= 0 && x0 < Wi) ? 1.f : 0.f;
    const float vx1 = (x0 + 1 >= 0 && x0 + 1 < Wi) ? 1.f : 0.f;
    const float vy0 = (y0 >= 0 && y0 < Hi) ? 1.f : 0.f;
    const float vy1 = (y0 + 1 >= 0 && y0 + 1 < Hi) ? 1.f : 0.f;
    const unsigned int* vl = vc + (size_t)LS[lvl] * 128;
    const unsigned int u00 = vl[(y0c * Wi + x0c) * 128];
    const unsigned int u01 = vl[(y0c * Wi + x1c) * 128];
    const unsigned int u10 = vl[(y1c * Wi + x0c) * 128];
    const unsigned int u11 = vl[(y1c * Wi + x1c) * 128];
    const float w00 = (1.f - fx) * (1.f - fy) * vx0 * vy0 * w;
    const float w01 = fx * (1.f - fy) * vx1 * vy0 * w;
    const float w10 = (1.f - fx) * fy * vx0 * vy1 * w;
    const float w11 = fx * fy * vx1 * vy1 * w;
    acc0 += w00 * bf_lo(u00) + w01 * bf_lo(u01) +
            w10 * bf_lo(u10) + w11 * bf_lo(u11);
    acc1 += w00 * bf_hi(u00) + w01 * bf_hi(u01) +
            w10 * bf_hi(u10) + w11 * bf_hi(u11);
  }
  atomicAdd(&slots[q * 256 + tt * 2], acc0);
  atomicAdd(&slots[q * 256 + tt * 2 + 1], acc1);
}

// ---------------------------------------------------------------------------
extern "C" void kernel_launch(void* const* d_in, const int* in_sizes, int n_in,
                              void* d_out, int out_size, void* d_ws,
                              size_t ws_size, hipStream_t stream) {
  const float* query  = (const float*)d_in[0];
  // d_in[1] = key : unused by the reference forward
  const float* value  = (const float*)d_in[2];
  const float* qpos   = (const float*)d_in[3];
  const float* refpts = (const float*)d_in[4];
  const void*  bmask  = d_in[5];
  const float* W_value = (const float*)d_in[8];
  const float* b_value = (const float*)d_in[9];
  const float* W_off   = (const float*)d_in[10];
  const float* b_off   = (const float*)d_in[11];
  const float* W_attn  = (const float*)d_in[12];
  const float* b_attn  = (const float*)d_in[13];
  const float* W_out   = (const float*)d_in[14];
  const float* b_out   = (const float*)d_in[15];
  float* out = (float*)d_out;

  // workspace layout (~71 MB)
  unsigned short* ws_v = (unsigned short*)d_ws;                    // M_VAL*256 bf16
  unsigned short* ws_wv   = ws_v + (size_t)M_VAL * 256;            // 65536
  unsigned short* ws_wq   = ws_wv + 65536;                         // 196608
  unsigned short* ws_wout = ws_wq + 196608;                        // 65536
  float* ws_offlog = (float*)(ws_wout + 65536);                    // NQ*768
  float* ws_slots  = ws_offlog + (size_t)NQ * 768;                 // NQ*256
  float* ws_invcnt = ws_slots + (size_t)NQ * 256;                  // NQ
  float* ws_bcat   = ws_invcnt + NQ;                               // 768
  unsigned char* ws_mask = (unsigned char*)(ws_bcat + 768);        // NCAMS*NQ

  canon_mask_kernel<<<60, 256, 0, stream>>>(bmask, ws_mask, ws_invcnt,
                                            b_off, b_attn, ws_bcat);
  cvt_weights_kernel<<<1280, 256, 0, stream>>>(
      W_value, W_off, W_attn, W_out, ws_wv, ws_wq, ws_wout);
  hipMemsetAsync(ws_slots, 0, (size_t)NQ * 256 * sizeof(float), stream);

  // v = value @ W_value^T + b_value   (117360 x 256), bf16 out
  gemm_mfma_kernel<true, false, false, false><<<dim3(1834, 2), 256, 0, stream>>>(
      value, nullptr, ws_wv, b_value, nullptr, nullptr, (void*)ws_v,
      M_VAL, 256);

  // [off | logits] = (q+qpos) @ [W_off;W_attn]^T + bcat   (2500 x 768)
  gemm_mfma_kernel<false, true, false, false><<<dim3(40, 6), 256, 0, stream>>>(
      query, qpos, ws_wq, ws_bcat, nullptr, nullptr, (void*)ws_offlog,
      NQ, 768);

  sampler3_kernel<<<NCAMS * NQ, 256, 0, stream>>>(
      ws_v, ws_offlog, refpts, ws_mask, ws_slots);

  // out = (slots/cnt) @ W_out^T + b_out + query   (2500 x 256)
  gemm_mfma_kernel<false, false, true, true><<<dim3(40, 2), 256, 0, stream>>>(
      ws_slots, nullptr, ws_wout, b_out, query, ws_invcnt, (void*)out,
      NQ, 256);
}

// Round 7
// 376.973 us; speedup vs baseline: 1.0502x; 1.0502x over previous
//
#include <hip/hip_runtime.h>
#include <hip/hip_bf16.h>

// Static problem config (BEVFormer-base-ish, 50x50 BEV grid)
#define L_TOT   19560
#define NQ      2500
#define NCAMS   6
#define M_VAL   (NCAMS * L_TOT)   // 117360

typedef __attribute__((ext_vector_type(8))) short short8;
typedef __attribute__((ext_vector_type(4))) float f32x4;

__device__ __forceinline__ unsigned short f2bf(float x) {
  __hip_bfloat16 h = __float2bfloat16(x);
  return *reinterpret_cast<unsigned short*>(&h);
}
__device__ __forceinline__ unsigned int pack2bf(float lo, float hi) {
  return (unsigned int)f2bf(lo) | ((unsigned int)f2bf(hi) << 16);
}
__device__ __forceinline__ float bf_lo(unsigned int u) {
  return __uint_as_float(u << 16);
}
__device__ __forceinline__ float bf_hi(unsigned int u) {
  return __uint_as_float(u & 0xffff0000u);
}

__device__ __forceinline__ unsigned char canon_bool(const void* in, int i,
                                                    int mode) {
  if (mode == 1) return (unsigned char)(((const unsigned int*)in)[i] != 0u);
  if (mode == 2) return (unsigned char)(((const float*)in)[i] != 0.0f);
  return (unsigned char)(((const unsigned char*)in)[i] != 0);
}

// ---------------------------------------------------------------------------
// Parallel bev_mask canonicalizer (bool may arrive as u8 / i32 / f32).
//  - all 60 blocks: canonical u8 mask slice
//  - blocks 0..9:   invcnt slice (250 q each)
//  - block 10:      bcat = [b_off(512); b_attn(256)]
//  - blocks 11..59: zero ws_slots (folded hipMemsetAsync — one fewer launch)
// ---------------------------------------------------------------------------
__global__ void canon_mask_kernel(const void* __restrict__ in,
                                  unsigned char* __restrict__ outm,
                                  float* __restrict__ invcnt,
                                  const float* __restrict__ b_off,
                                  const float* __restrict__ b_attn,
                                  float* __restrict__ bcat,
                                  float* __restrict__ slots) {
  __shared__ int notI, notF;
  if (threadIdx.x == 0) { notI = 0; notF = 0; }
  __syncthreads();
  const unsigned int* w = (const unsigned int*)in;
  for (int i = threadIdx.x; i < 3750; i += 256) {
    unsigned int x = w[i];
    if (x != 0u && x != 1u)          atomicOr(&notI, 1);
    if (x != 0u && x != 0x3f800000u) atomicOr(&notF, 1);
  }
  __syncthreads();
  const int mode = (notI == 0) ? 1 : ((notF == 0) ? 2 : 0);

  const int i = blockIdx.x * 256 + threadIdx.x;
  if (i < NCAMS * NQ) outm[i] = canon_bool(in, i, mode);

  if (blockIdx.x < 10) {
    const int q0 = blockIdx.x * 250;
    for (int q = q0 + threadIdx.x; q < q0 + 250; q += 256) {
      int cnt = 0;
#pragma unroll
      for (int c = 0; c < NCAMS; ++c) cnt += canon_bool(in, c * NQ + q, mode);
      invcnt[q] = 1.f / (float)max(cnt, 1);
    }
  } else if (blockIdx.x == 10) {
    for (int j = threadIdx.x; j < 768; j += 256)
      bcat[j] = (j < 512) ? b_off[j] : b_attn[j - 512];
  } else {
    // zero slots: NQ*256 floats = 160000 float4s over 49 blocks
    float4* s4 = (float4*)slots;
    const float4 z = make_float4(0.f, 0.f, 0.f, 0.f);
    for (int j = (blockIdx.x - 11) * 256 + threadIdx.x; j < NQ * 64;
         j += 49 * 256)
      s4[j] = z;
  }
}

// ---------------------------------------------------------------------------
// Convert weights to bf16: W_value -> o0[65536]; [W_off;W_attn] -> o1[196608];
// W_out -> o2[65536].
// ---------------------------------------------------------------------------
__global__ void cvt_weights_kernel(const float* __restrict__ wv,
                                   const float* __restrict__ woff,
                                   const float* __restrict__ wattn,
                                   const float* __restrict__ wout,
                                   unsigned short* __restrict__ o0,
                                   unsigned short* __restrict__ o1,
                                   unsigned short* __restrict__ o2) {
  int i = blockIdx.x * 256 + threadIdx.x;
  if (i < 65536)        o0[i] = f2bf(wv[i]);
  else if (i < 196608)  o1[i - 65536] = f2bf(woff[i - 65536]);
  else if (i < 262144)  o1[131072 + (i - 196608)] = f2bf(wattn[i - 196608]);
  else if (i < 327680)  o2[i - 262144] = f2bf(wout[i - 262144]);
}

// ---------------------------------------------------------------------------
// bf16-MFMA GEMM, 64x128 tile, RAW COUNTED-VMCNT BARRIERS, 1-DEEP STAGING:
//   C[m, ch] = sum_k bf16(scale[m]*(A[m,k]+A2[m,k])) * W[ch,k] + bias[ch]
//              (+ R[m,ch])
// ROUND-7 — clean decomposition of rounds 4/6:
//  r4 (__syncthreads, 1-deep): 87us, 2.08 TB/s, traffic clean.  The
//    compiler's vmcnt(0)-before-s_barrier drained prefetched loads every
//    iteration -> pipeline depth 0.
//  r6 (raw barriers, 2-deep):  99us, 2.41 TB/s raw (+16% — the barrier
//    mechanism WORKS) but the 2nd staging set spilled: WRITE 59->99MB.
//  r7 = raw barriers + r4's 1-deep registers (40 arch + 32 acc, proven
//    spill-free). lgkmcnt(0)-only fences at barriers; NO vmcnt(0) in loop;
//    the wait for staged regs materializes as a counted vmcnt at STORE.
// Barrier discipline (single-buffered LDS, 2 barriers/iter):
//  - fence lgkmcnt(0) + barrier BEFORE ds_writes: all waves' ds_reads of the
//    prev tile retired (no read-overwrite race).
//  - fence lgkmcnt(0) + barrier AFTER ds_writes: writes visible to readers.
//  ds_reads/ds_writes can't cross the asm ("memory" clobber); MFMAs are
//  register-only and data-dependent on the reads -> safe (r6 absmax ok).
// Ledger (r3 lesson): unified VGPR+AGPR, (arch+agpr)*waves/SIMD <= 512;
// (256,5) cap=102 vs ~72 used.
// Tripwires: WRITE_SIZE>70MB = spill (abandon raw-barrier lane);
//            absmax>0.0157 = barrier race (revert to __syncthreads).
// ---------------------------------------------------------------------------
template <bool BF16_OUT, bool HAS_A2, bool HAS_RES, bool HAS_SCALE>
__global__ __launch_bounds__(256, 5) void gemm_mfma_kernel(
    const float* __restrict__ A, const float* __restrict__ A2,
    const unsigned short* __restrict__ Wbf, const float* __restrict__ bias,
    const float* __restrict__ R, const float* __restrict__ rowscale,
    void* __restrict__ Cv, int M, int N) {
  __shared__ unsigned short As[64 * 40];   // data rows (bf16), pad to 40
  __shared__ unsigned short Bs[128 * 40];  // weight rows (channels)
  const int tid = threadIdx.x;
  const int m0 = blockIdx.x * 64;
  const int n0 = blockIdx.y * 128;
  const int wave = tid >> 6;
  const int lane = tid & 63;
  const int wr = (wave >> 1) * 32;  // row-block within tile (0/32)
  const int wc = (wave & 1) * 64;   // channel-block within tile (0/64)
  const int fr = lane & 15;
  const int fg = lane >> 4;

  // A staging: thread -> (row 0..63, 8-element quarter of the 32-k tile)
  const int sr = tid >> 2;
  const int sc = (tid & 3) * 8;
  const bool a_ok = (m0 + sr) < M;
  const float* Ap = A + (size_t)(m0 + sr) * 256 + sc;
  const float* A2p = HAS_A2 ? (A2 + (size_t)(m0 + sr) * 256 + sc) : nullptr;
  const float ascale = (HAS_SCALE && a_ok) ? rowscale[m0 + sr] : 1.f;
  unsigned short* asw = &As[sr * 40 + sc];

  // B staging: thread -> (channel 0..127, 16-element half of the 32-k tile)
  const int br = tid >> 1;
  const int bc = (tid & 1) * 16;
  const unsigned short* Bp = Wbf + (size_t)(n0 + br) * 256 + bc;
  unsigned short* bsw = &Bs[br * 40 + bc];

  f32x4 acc[4][2] = {};  // [ct(channel)][rt(row)] — 32 AGPR

  // 1-deep register staging (round-4 footprint, spill-free)
  float4 ra[2], rt[2];
  uint4 rb0, rb1;

#define GEMM_ISSUE(KT)                                                     \
  {                                                                        \
    ra[0] = a_ok ? *(const float4*)(Ap + (KT) * 32)                        \
                 : make_float4(0.f, 0.f, 0.f, 0.f);                        \
    ra[1] = a_ok ? *(const float4*)(Ap + (KT) * 32 + 4)                    \
                 : make_float4(0.f, 0.f, 0.f, 0.f);                        \
    if (HAS_A2) {                                                          \
      rt[0] = a_ok ? *(const float4*)(A2p + (KT) * 32)                     \
                   : make_float4(0.f, 0.f, 0.f, 0.f);                      \
      rt[1] = a_ok ? *(const float4*)(A2p + (KT) * 32 + 4)                 \
                   : make_float4(0.f, 0.f, 0.f, 0.f);                      \
    }                                                                      \
    rb0 = *(const uint4*)(Bp + (KT) * 32);                                 \
    rb1 = *(const uint4*)(Bp + (KT) * 32 + 8);                             \
  }

// lgkmcnt-only fence + raw barrier: NO vmcnt drain (the whole point).
#define GEMM_FENCE_BARRIER()                                               \
  asm volatile("s_waitcnt lgkmcnt(0)" ::: "memory");                       \
  __builtin_amdgcn_s_barrier();

  GEMM_ISSUE(0);

  for (int kt = 0; kt < 8; ++kt) {
    GEMM_FENCE_BARRIER();  // prev tile's ds_reads retired in all waves
    // STORE: process regs -> bf16 -> LDS
    {
      float4 s0 = ra[0], s1 = ra[1];
      if (HAS_A2) {
        s0.x += rt[0].x; s0.y += rt[0].y; s0.z += rt[0].z; s0.w += rt[0].w;
        s1.x += rt[1].x; s1.y += rt[1].y; s1.z += rt[1].z; s1.w += rt[1].w;
      }
      if (HAS_SCALE) {
        s0.x *= ascale; s0.y *= ascale; s0.z *= ascale; s0.w *= ascale;
        s1.x *= ascale; s1.y *= ascale; s1.z *= ascale; s1.w *= ascale;
      }
      uint4 u0;
      u0.x = pack2bf(s0.x, s0.y); u0.y = pack2bf(s0.z, s0.w);
      u0.z = pack2bf(s1.x, s1.y); u0.w = pack2bf(s1.z, s1.w);
      *(uint4*)asw = u0;
      *(uint4*)bsw = rb0;
      *(uint4*)(bsw + 8) = rb1;
    }
    GEMM_FENCE_BARRIER();  // ds_writes visible to all waves

    if (kt < 7) GEMM_ISSUE(kt + 1);  // in flight across MFMA + both barriers

    short8 wf[4], vf[2];
#pragma unroll
    for (int ct = 0; ct < 4; ++ct)
      wf[ct] = *(const short8*)&Bs[(wc + ct * 16 + fr) * 40 + fg * 8];
#pragma unroll
    for (int rt2 = 0; rt2 < 2; ++rt2)
      vf[rt2] = *(const short8*)&As[(wr + rt2 * 16 + fr) * 40 + fg * 8];
#pragma unroll
    for (int ct = 0; ct < 4; ++ct)
#pragma unroll
      for (int rt2 = 0; rt2 < 2; ++rt2)
        acc[ct][rt2] = __builtin_amdgcn_mfma_f32_16x16x32_bf16(
            wf[ct], vf[rt2], acc[ct][rt2], 0, 0, 0);
  }
#undef GEMM_ISSUE
#undef GEMM_FENCE_BARRIER

  // Epilogue: D layout -> data row = fr, channel = fg*4 + reg
#pragma unroll
  for (int rt2 = 0; rt2 < 2; ++rt2) {
    const int m = m0 + wr + rt2 * 16 + fr;
    if (m >= M) continue;
#pragma unroll
    for (int ct = 0; ct < 4; ++ct) {
      const int ch = n0 + wc + ct * 16 + fg * 4;
      float o[4];
#pragma unroll
      for (int r = 0; r < 4; ++r) o[r] = acc[ct][rt2][r] + bias[ch + r];
      if (HAS_RES) {
        const float4 r4 = *(const float4*)&R[(size_t)m * N + ch];
        o[0] += r4.x; o[1] += r4.y; o[2] += r4.z; o[3] += r4.w;
      }
      if (BF16_OUT) {
        ushort4 u;
        u.x = f2bf(o[0]); u.y = f2bf(o[1]); u.z = f2bf(o[2]); u.w = f2bf(o[3]);
        *(ushort4*)((unsigned short*)Cv + (size_t)m * N + ch) = u;
      } else {
        float4 of; of.x = o[0]; of.y = o[1]; of.z = o[2]; of.w = o[3];
        *(float4*)((float*)Cv + (size_t)m * N + ch) = of;
      }
    }
  }
}

// ---------------------------------------------------------------------------
// Sampler v3: one block per (cam, query) pair; 256 threads = 2 sample-groups
// of 128 threads (2 channels each).
// ---------------------------------------------------------------------------
__global__ __launch_bounds__(256) void sampler3_kernel(
    const unsigned short* __restrict__ v, const float* __restrict__ offlog,
    const float* __restrict__ ref, const unsigned char* __restrict__ mask,
    float* __restrict__ slots) {
  const int pair = blockIdx.x;                 // c * NQ + q
  if (!mask[pair]) return;
  const int c = pair / NQ;
  const int q = pair - c * NQ;
  const int t = threadIdx.x;                   // 0..255

  __shared__ float sx[256], sy[256], sw[256];
  {
    const float Wl[4] = {160.f, 80.f, 40.f, 20.f};
    const float Hl[4] = {92.f, 46.f, 23.f, 12.f};
    const int combo = t;                       // (h,l,p): h=combo>>5
    const int l = (combo >> 3) & 3;
    const int p = combo & 7;
    const int z = p & 3;                       // NP//NZ x NZ reshape
    const float2 rz = ((const float2*)ref)[q * 4 + z];
    const float2 o2 = ((const float2*)offlog)[(size_t)q * 384 + combo];
    sx[combo] = rz.x * Wl[l] + o2.x - 0.5f;
    sy[combo] = rz.y * Hl[l] + o2.y - 0.5f;
    float lg = offlog[(size_t)q * 768 + 512 + combo];
    float mx = lg;
    for (int s = 16; s; s >>= 1) mx = fmaxf(mx, __shfl_xor(mx, s, 32));
    float e = __expf(lg - mx);
    float sm = e;
    for (int s = 16; s; s >>= 1) sm += __shfl_xor(sm, s, 32);
    sw[combo] = e / sm;
  }
  __syncthreads();

  const int WW[4] = {160, 80, 40, 20};
  const int HH[4] = {92, 46, 23, 12};
  const int LS[4] = {0, 14720, 18400, 19320};

  const int tt = t & 127;                      // channel pair
  const int grp = t >> 7;                      // sample group
  const unsigned int* vc =
      (const unsigned int*)(v + (size_t)c * (L_TOT * 256)) + tt;
  const int cbase = (tt >> 4) * 32;
  const int sbase = grp * 16;
  float acc0 = 0.f, acc1 = 0.f;

#pragma unroll
  for (int j = 0; j < 16; ++j) {
    const int s = sbase + j;
    const int lvl = s >> 3;
    const int combo = cbase + s;
    const float x = sx[combo], y = sy[combo], w = sw[combo];
    const float fx0 = floorf(x), fy0 = floorf(y);
    const float fx = x - fx0, fy = y - fy0;
    const int x0 = (int)fx0, y0 = (int)fy0;
    const int Wi = WW[lvl], Hi = HH[lvl];
    const int x0c = min(max(x0, 0), Wi - 1);
    const int x1c = min(max(x0 + 1, 0), Wi - 1);
    const int y0c = min(max(y0, 0), Hi - 1);
    const int y1c = min(max(y0 + 1, 0), Hi - 1);
    const float vx0 = (x0 >= 0 && x0 < Wi) ? 1.f : 0.f;
    const float vx1 = (x0 + 1 >= 0 && x0 + 1 < Wi) ? 1.f : 0.f;
    const float vy0 = (y0 >= 0 && y0 < Hi) ? 1.f : 0.f;
    const float vy1 = (y0 + 1 >= 0 && y0 + 1 < Hi) ? 1.f : 0.f;
    const unsigned int* vl = vc + (size_t)LS[lvl] * 128;
    const unsigned int u00 = vl[(y0c * Wi + x0c) * 128];
    const unsigned int u01 = vl[(y0c * Wi + x1c) * 128];
    const unsigned int u10 = vl[(y1c * Wi + x0c) * 128];
    const unsigned int u11 = vl[(y1c * Wi + x1c) * 128];
    const float w00 = (1.f - fx) * (1.f - fy) * vx0 * vy0 * w;
    const float w01 = fx * (1.f - fy) * vx1 * vy0 * w;
    const float w10 = (1.f - fx) * fy * vx0 * vy1 * w;
    const float w11 = fx * fy * vx1 * vy1 * w;
    acc0 += w00 * bf_lo(u00) + w01 * bf_lo(u01) +
            w10 * bf_lo(u10) + w11 * bf_lo(u11);
    acc1 += w00 * bf_hi(u00) + w01 * bf_hi(u01) +
            w10 * bf_hi(u10) + w11 * bf_hi(u11);
  }
  atomicAdd(&slots[q * 256 + tt * 2], acc0);
  atomicAdd(&slots[q * 256 + tt * 2 + 1], acc1);
}

// ---------------------------------------------------------------------------
extern "C" void kernel_launch(void* const* d_in, const int* in_sizes, int n_in,
                              void* d_out, int out_size, void* d_ws,
                              size_t ws_size, hipStream_t stream) {
  const float* query  = (const float*)d_in[0];
  // d_in[1] = key : unused by the reference forward
  const float* value  = (const float*)d_in[2];
  const float* qpos   = (const float*)d_in[3];
  const float* refpts = (const float*)d_in[4];
  const void*  bmask  = d_in[5];
  const float* W_value = (const float*)d_in[8];
  const float* b_value = (const float*)d_in[9];
  const float* W_off   = (const float*)d_in[10];
  const float* b_off   = (const float*)d_in[11];
  const float* W_attn  = (const float*)d_in[12];
  const float* b_attn  = (const float*)d_in[13];
  const float* W_out   = (const float*)d_in[14];
  const float* b_out   = (const float*)d_in[15];
  float* out = (float*)d_out;

  // workspace layout (~71 MB)
  unsigned short* ws_v = (unsigned short*)d_ws;                    // M_VAL*256 bf16
  unsigned short* ws_wv   = ws_v + (size_t)M_VAL * 256;            // 65536
  unsigned short* ws_wq   = ws_wv + 65536;                         // 196608
  unsigned short* ws_wout = ws_wq + 196608;                        // 65536
  float* ws_offlog = (float*)(ws_wout + 65536);                    // NQ*768
  float* ws_slots  = ws_offlog + (size_t)NQ * 768;                 // NQ*256
  float* ws_invcnt = ws_slots + (size_t)NQ * 256;                  // NQ
  float* ws_bcat   = ws_invcnt + NQ;                               // 768
  unsigned char* ws_mask = (unsigned char*)(ws_bcat + 768);        // NCAMS*NQ

  canon_mask_kernel<<<60, 256, 0, stream>>>(bmask, ws_mask, ws_invcnt,
                                            b_off, b_attn, ws_bcat, ws_slots);
  cvt_weights_kernel<<<1280, 256, 0, stream>>>(
      W_value, W_off, W_attn, W_out, ws_wv, ws_wq, ws_wout);

  // v = value @ W_value^T + b_value   (117360 x 256), bf16 out
  gemm_mfma_kernel<true, false, false, false><<<dim3(1834, 2), 256, 0, stream>>>(
      value, nullptr, ws_wv, b_value, nullptr, nullptr, (void*)ws_v,
      M_VAL, 256);

  // [off | logits] = (q+qpos) @ [W_off;W_attn]^T + bcat   (2500 x 768)
  gemm_mfma_kernel<false, true, false, false><<<dim3(40, 6), 256, 0, stream>>>(
      query, qpos, ws_wq, ws_bcat, nullptr, nullptr, (void*)ws_offlog,
      NQ, 768);

  sampler3_kernel<<<NCAMS * NQ, 256, 0, stream>>>(
      ws_v, ws_offlog, refpts, ws_mask, ws_slots);

  // out = (slots/cnt) @ W_out^T + b_out + query   (2500 x 256)
  gemm_mfma_kernel<false, false, true, true><<<dim3(40, 2), 256, 0, stream>>>(
      ws_slots, nullptr, ws_wout, b_out, query, ws_invcnt, (void*)out,
      NQ, 256);
}

// Round 8
// 366.914 us; speedup vs baseline: 1.0790x; 1.0274x over previous
//
#include <hip/hip_runtime.h>
#include <hip/hip_bf16.h>

// Static problem config (BEVFormer-base-ish, 50x50 BEV grid)
#define L_TOT   19560
#define NQ      2500
#define NCAMS   6
#define M_VAL   (NCAMS * L_TOT)   // 117360

typedef __attribute__((ext_vector_type(8))) short short8;
typedef __attribute__((ext_vector_type(4))) float f32x4;

__device__ __forceinline__ unsigned short f2bf(float x) {
  __hip_bfloat16 h = __float2bfloat16(x);
  return *reinterpret_cast<unsigned short*>(&h);
}
__device__ __forceinline__ unsigned int pack2bf(float lo, float hi) {
  return (unsigned int)f2bf(lo) | ((unsigned int)f2bf(hi) << 16);
}
__device__ __forceinline__ float bf_lo(unsigned int u) {
  return __uint_as_float(u << 16);
}
__device__ __forceinline__ float bf_hi(unsigned int u) {
  return __uint_as_float(u & 0xffff0000u);
}

__device__ __forceinline__ unsigned char canon_bool(const void* in, int i,
                                                    int mode) {
  if (mode == 1) return (unsigned char)(((const unsigned int*)in)[i] != 0u);
  if (mode == 2) return (unsigned char)(((const float*)in)[i] != 0.0f);
  return (unsigned char)(((const unsigned char*)in)[i] != 0);
}

// ---------------------------------------------------------------------------
// Parallel bev_mask canonicalizer (bool may arrive as u8 / i32 / f32).
//  - all 60 blocks: canonical u8 mask slice
//  - blocks 0..9:   invcnt slice (250 q each)
//  - block 10:      bcat = [b_off(512); b_attn(256)]
//  - blocks 11..59: zero ws_slots (folded hipMemsetAsync)
// ---------------------------------------------------------------------------
__global__ void canon_mask_kernel(const void* __restrict__ in,
                                  unsigned char* __restrict__ outm,
                                  float* __restrict__ invcnt,
                                  const float* __restrict__ b_off,
                                  const float* __restrict__ b_attn,
                                  float* __restrict__ bcat,
                                  float* __restrict__ slots) {
  __shared__ int notI, notF;
  if (threadIdx.x == 0) { notI = 0; notF = 0; }
  __syncthreads();
  const unsigned int* w = (const unsigned int*)in;
  for (int i = threadIdx.x; i < 3750; i += 256) {
    unsigned int x = w[i];
    if (x != 0u && x != 1u)          atomicOr(&notI, 1);
    if (x != 0u && x != 0x3f800000u) atomicOr(&notF, 1);
  }
  __syncthreads();
  const int mode = (notI == 0) ? 1 : ((notF == 0) ? 2 : 0);

  const int i = blockIdx.x * 256 + threadIdx.x;
  if (i < NCAMS * NQ) outm[i] = canon_bool(in, i, mode);

  if (blockIdx.x < 10) {
    const int q0 = blockIdx.x * 250;
    for (int q = q0 + threadIdx.x; q < q0 + 250; q += 256) {
      int cnt = 0;
#pragma unroll
      for (int c = 0; c < NCAMS; ++c) cnt += canon_bool(in, c * NQ + q, mode);
      invcnt[q] = 1.f / (float)max(cnt, 1);
    }
  } else if (blockIdx.x == 10) {
    for (int j = threadIdx.x; j < 768; j += 256)
      bcat[j] = (j < 512) ? b_off[j] : b_attn[j - 512];
  } else {
    float4* s4 = (float4*)slots;
    const float4 z = make_float4(0.f, 0.f, 0.f, 0.f);
    for (int j = (blockIdx.x - 11) * 256 + threadIdx.x; j < NQ * 64;
         j += 49 * 256)
      s4[j] = z;
  }
}

// ---------------------------------------------------------------------------
// Convert weights to bf16: W_value -> o0[65536]; [W_off;W_attn] -> o1[196608];
// W_out -> o2[65536].
// ---------------------------------------------------------------------------
__global__ void cvt_weights_kernel(const float* __restrict__ wv,
                                   const float* __restrict__ woff,
                                   const float* __restrict__ wattn,
                                   const float* __restrict__ wout,
                                   unsigned short* __restrict__ o0,
                                   unsigned short* __restrict__ o1,
                                   unsigned short* __restrict__ o2) {
  int i = blockIdx.x * 256 + threadIdx.x;
  if (i < 65536)        o0[i] = f2bf(wv[i]);
  else if (i < 196608)  o1[i - 65536] = f2bf(woff[i - 65536]);
  else if (i < 262144)  o1[131072 + (i - 196608)] = f2bf(wattn[i - 196608]);
  else if (i < 327680)  o2[i - 262144] = f2bf(wout[i - 262144]);
}

// ---------------------------------------------------------------------------
// Value GEMM via ASYNC global_load_lds + double-buffered LDS + counted vmcnt:
//   C[m,ch] = bf16( sum_k bf16(A[m,k]) * W[ch,k] + bias[ch] ),  K=N=256.
// ROUND-8 rationale: rounds 4/6/7 proved register-staged pipelines can't get
// deeper than 1 without spilling (depth costs regs x depth), and depth-1
// exposes ~600cy HBM latency per K-tile regardless of barrier flavor.
// global_load_lds moves HBM->LDS with ZERO VGPR cost -> depth-2 is free:
//   prologue: issue tile0, tile1 (4 instrs each, 16B/lane)
//   iter kt:  vmcnt(4)[tile kt landed] -> barrier -> ds_read frags ->
//             lgkmcnt(0) -> barrier -> issue tile kt+2 -> cvt + 8 MFMA
// Each tile has a FULL iteration of latency cover; no vmcnt(0) until kt=7.
// A stays fp32 in LDS (cvt_pk to bf16 after ds_read; VALU has headroom).
// gload_lds writes linearly (wave-uniform base + lane*16) -> no pad allowed;
// bank conflicts fixed by XOR slot swizzle, applied BOTH sides (rule #21):
//   A[64][32]f32 (128B rows, 8x16B slots):  phys_slot = logical ^ (row&7)
//   B[128][32]bf16 (64B rows, 4x16B slots): phys_slot = logical ^ ((row>>1)&3)
// source lanes fetch logical=phys^bits; ds_read uses phys=logical^bits.
// LDS 2*(8K+8K)=32KB/block; regs ~70 arch + 32 acc -> (256,4) cap 128.
// Tripwires: absmax>0.0157 = swizzle/race bug; WRITE>70MB = spill.
// ---------------------------------------------------------------------------
#define GLOAD_LDS16(G, L)                                                   \
  __builtin_amdgcn_global_load_lds(                                         \
      (const __attribute__((address_space(1))) unsigned int*)(G),           \
      (__attribute__((address_space(3))) unsigned int*)(L), 16, 0, 0)

__global__ __launch_bounds__(256, 4) void vgemm_async_kernel(
    const float* __restrict__ A, const unsigned short* __restrict__ Wbf,
    const float* __restrict__ bias, unsigned short* __restrict__ C,
    const int M) {
  __shared__ float Asf[2][64 * 32];           // 2 x 8 KB fp32
  __shared__ unsigned short Bsf[2][128 * 32]; // 2 x 8 KB bf16

  const int tid = threadIdx.x;
  const int w = tid >> 6;
  const int l = tid & 63;
  const int m0 = blockIdx.x * 64;
  const int n0 = blockIdx.y * 128;
  const int fr = l & 15;
  const int fg = l >> 4;
  const int wr = (w >> 1) * 32;   // row-block within tile (0/32)
  const int wc = (w & 1) * 64;    // channel-block within tile (0/64)

  // ---- staging source pointers (per-lane, inverse-swizzled) ----
  const int l8 = l >> 3;          // 0..7
  const int arow0 = w * 16 + l8;  // A rows, instr j=0 / j=1
  const int aslot = ((l & 7) ^ l8) << 4;
  const char* ga0 = (const char*)A + (size_t)min(m0 + arow0, M - 1) * 1024 + aslot;
  const char* ga1 = (const char*)A + (size_t)min(m0 + arow0 + 8, M - 1) * 1024 + aslot;
  const int bch0 = n0 + w * 32 + (l >> 2);
  const int bslot = ((l & 3) ^ (l8 & 3)) << 4;
  const char* gb0 = (const char*)Wbf + (size_t)bch0 * 512 + bslot;
  const char* gb1 = gb0 + 16 * 512;
  // LDS dest (wave-uniform; lane writes base + lane*16)
  const int ldsW = w * 2048;
  char* AsfB = (char*)Asf;
  char* BsfB = (char*)Bsf;

  // ---- ds_read byte offsets (swizzled) ----
  int aoff[2][2], boff[4];
#pragma unroll
  for (int rt2 = 0; rt2 < 2; ++rt2) {
    const int row = wr + rt2 * 16 + fr;
    aoff[rt2][0] = row * 128 + (((fg * 2) ^ (fr & 7)) << 4);
    aoff[rt2][1] = row * 128 + (((fg * 2 + 1) ^ (fr & 7)) << 4);
  }
#pragma unroll
  for (int ct = 0; ct < 4; ++ct) {
    const int ch = wc + ct * 16 + fr;
    boff[ct] = ch * 64 + ((fg ^ ((fr >> 1) & 3)) << 4);
  }

  f32x4 acc[4][2] = {};  // [ct(channel)][rt(row)] — 32 AGPR

#define VG_ISSUE(KT)                                                       \
  {                                                                        \
    char* Ad_ = AsfB + (((KT) & 1) * 8192) + ldsW;                         \
    char* Bd_ = BsfB + (((KT) & 1) * 8192) + ldsW;                         \
    GLOAD_LDS16(ga0 + (KT) * 128, Ad_);                                    \
    GLOAD_LDS16(ga1 + (KT) * 128, Ad_ + 1024);                             \
    GLOAD_LDS16(gb0 + (KT) * 64, Bd_);                                     \
    GLOAD_LDS16(gb1 + (KT) * 64, Bd_ + 1024);                              \
  }

#define VG_STEP(KT, WAITN, ISS)                                            \
  {                                                                        \
    asm volatile("s_waitcnt vmcnt(" #WAITN ")" ::: "memory");              \
    __builtin_amdgcn_s_barrier(); /* tile KT complete in all waves */      \
    const char* Ab_ = AsfB + (((KT) & 1) * 8192);                          \
    const char* Bb_ = BsfB + (((KT) & 1) * 8192);                          \
    const float4 a00 = *(const float4*)(Ab_ + aoff[0][0]);                 \
    const float4 a01 = *(const float4*)(Ab_ + aoff[0][1]);                 \
    const float4 a10 = *(const float4*)(Ab_ + aoff[1][0]);                 \
    const float4 a11 = *(const float4*)(Ab_ + aoff[1][1]);                 \
    const short8 wf0 = *(const short8*)(Bb_ + boff[0]);                    \
    const short8 wf1 = *(const short8*)(Bb_ + boff[1]);                    \
    const short8 wf2 = *(const short8*)(Bb_ + boff[2]);                    \
    const short8 wf3 = *(const short8*)(Bb_ + boff[3]);                    \
    asm volatile("s_waitcnt lgkmcnt(0)" ::: "memory");                     \
    if (ISS) {                                                             \
      __builtin_amdgcn_s_barrier(); /* all waves done reading buf */       \
      VG_ISSUE((KT) + 2);                                                  \
    }                                                                      \
    uint4 u0, u1;                                                          \
    u0.x = pack2bf(a00.x, a00.y); u0.y = pack2bf(a00.z, a00.w);            \
    u0.z = pack2bf(a01.x, a01.y); u0.w = pack2bf(a01.z, a01.w);            \
    u1.x = pack2bf(a10.x, a10.y); u1.y = pack2bf(a10.z, a10.w);            \
    u1.z = pack2bf(a11.x, a11.y); u1.w = pack2bf(a11.z, a11.w);            \
    const short8 vf0 = *(short8*)&u0;                                      \
    const short8 vf1 = *(short8*)&u1;                                      \
    acc[0][0] = __builtin_amdgcn_mfma_f32_16x16x32_bf16(wf0, vf0, acc[0][0], 0, 0, 0); \
    acc[0][1] = __builtin_amdgcn_mfma_f32_16x16x32_bf16(wf0, vf1, acc[0][1], 0, 0, 0); \
    acc[1][0] = __builtin_amdgcn_mfma_f32_16x16x32_bf16(wf1, vf0, acc[1][0], 0, 0, 0); \
    acc[1][1] = __builtin_amdgcn_mfma_f32_16x16x32_bf16(wf1, vf1, acc[1][1], 0, 0, 0); \
    acc[2][0] = __builtin_amdgcn_mfma_f32_16x16x32_bf16(wf2, vf0, acc[2][0], 0, 0, 0); \
    acc[2][1] = __builtin_amdgcn_mfma_f32_16x16x32_bf16(wf2, vf1, acc[2][1], 0, 0, 0); \
    acc[3][0] = __builtin_amdgcn_mfma_f32_16x16x32_bf16(wf3, vf0, acc[3][0], 0, 0, 0); \
    acc[3][1] = __builtin_amdgcn_mfma_f32_16x16x32_bf16(wf3, vf1, acc[3][1], 0, 0, 0); \
  }

  VG_ISSUE(0);
  VG_ISSUE(1);

  VG_STEP(0, 4, true);
  VG_STEP(1, 4, true);
  VG_STEP(2, 4, true);
  VG_STEP(3, 4, true);
  VG_STEP(4, 4, true);
  VG_STEP(5, 4, true);
  VG_STEP(6, 4, false);
  VG_STEP(7, 0, false);

#undef VG_ISSUE
#undef VG_STEP

  // Epilogue: D layout -> data row = fr, channel = fg*4 + reg
#pragma unroll
  for (int rt2 = 0; rt2 < 2; ++rt2) {
    const int m = m0 + wr + rt2 * 16 + fr;
    if (m >= M) continue;
#pragma unroll
    for (int ct = 0; ct < 4; ++ct) {
      const int ch = n0 + wc + ct * 16 + fg * 4;
      const float4 b4 = *(const float4*)&bias[ch];
      ushort4 u;
      u.x = f2bf(acc[ct][rt2][0] + b4.x);
      u.y = f2bf(acc[ct][rt2][1] + b4.y);
      u.z = f2bf(acc[ct][rt2][2] + b4.z);
      u.w = f2bf(acc[ct][rt2][3] + b4.w);
      *(ushort4*)(C + (size_t)m * 256 + ch) = u;
    }
  }
}

// ---------------------------------------------------------------------------
// bf16-MFMA GEMM (register 1-deep staging, raw lgkmcnt-only barriers) — used
// for the two SMALL GEMMs only (offlog 2500x768, out 2500x256).
// ---------------------------------------------------------------------------
template <bool BF16_OUT, bool HAS_A2, bool HAS_RES, bool HAS_SCALE>
__global__ __launch_bounds__(256, 5) void gemm_mfma_kernel(
    const float* __restrict__ A, const float* __restrict__ A2,
    const unsigned short* __restrict__ Wbf, const float* __restrict__ bias,
    const float* __restrict__ R, const float* __restrict__ rowscale,
    void* __restrict__ Cv, int M, int N) {
  __shared__ unsigned short As[64 * 40];   // data rows (bf16), pad to 40
  __shared__ unsigned short Bs[128 * 40];  // weight rows (channels)
  const int tid = threadIdx.x;
  const int m0 = blockIdx.x * 64;
  const int n0 = blockIdx.y * 128;
  const int wave = tid >> 6;
  const int lane = tid & 63;
  const int wr = (wave >> 1) * 32;  // row-block within tile (0/32)
  const int wc = (wave & 1) * 64;   // channel-block within tile (0/64)
  const int fr = lane & 15;
  const int fg = lane >> 4;

  // A staging: thread -> (row 0..63, 8-element quarter of the 32-k tile)
  const int sr = tid >> 2;
  const int sc = (tid & 3) * 8;
  const bool a_ok = (m0 + sr) < M;
  const float* Ap = A + (size_t)(m0 + sr) * 256 + sc;
  const float* A2p = HAS_A2 ? (A2 + (size_t)(m0 + sr) * 256 + sc) : nullptr;
  const float ascale = (HAS_SCALE && a_ok) ? rowscale[m0 + sr] : 1.f;
  unsigned short* asw = &As[sr * 40 + sc];

  // B staging: thread -> (channel 0..127, 16-element half of the 32-k tile)
  const int br = tid >> 1;
  const int bc = (tid & 1) * 16;
  const unsigned short* Bp = Wbf + (size_t)(n0 + br) * 256 + bc;
  unsigned short* bsw = &Bs[br * 40 + bc];

  f32x4 acc[4][2] = {};  // [ct(channel)][rt(row)] — 32 AGPR

  float4 ra[2], rt[2];
  uint4 rb0, rb1;

#define GEMM_ISSUE(KT)                                                     \
  {                                                                        \
    ra[0] = a_ok ? *(const float4*)(Ap + (KT) * 32)                        \
                 : make_float4(0.f, 0.f, 0.f, 0.f);                        \
    ra[1] = a_ok ? *(const float4*)(Ap + (KT) * 32 + 4)                    \
                 : make_float4(0.f, 0.f, 0.f, 0.f);                        \
    if (HAS_A2) {                                                          \
      rt[0] = a_ok ? *(const float4*)(A2p + (KT) * 32)                     \
                   : make_float4(0.f, 0.f, 0.f, 0.f);                      \
      rt[1] = a_ok ? *(const float4*)(A2p + (KT) * 32 + 4)                 \
                   : make_float4(0.f, 0.f, 0.f, 0.f);                      \
    }                                                                      \
    rb0 = *(const uint4*)(Bp + (KT) * 32);                                 \
    rb1 = *(const uint4*)(Bp + (KT) * 32 + 8);                             \
  }

#define GEMM_FENCE_BARRIER()                                               \
  asm volatile("s_waitcnt lgkmcnt(0)" ::: "memory");                       \
  __builtin_amdgcn_s_barrier();

  GEMM_ISSUE(0);

  for (int kt = 0; kt < 8; ++kt) {
    GEMM_FENCE_BARRIER();
    {
      float4 s0 = ra[0], s1 = ra[1];
      if (HAS_A2) {
        s0.x += rt[0].x; s0.y += rt[0].y; s0.z += rt[0].z; s0.w += rt[0].w;
        s1.x += rt[1].x; s1.y += rt[1].y; s1.z += rt[1].z; s1.w += rt[1].w;
      }
      if (HAS_SCALE) {
        s0.x *= ascale; s0.y *= ascale; s0.z *= ascale; s0.w *= ascale;
        s1.x *= ascale; s1.y *= ascale; s1.z *= ascale; s1.w *= ascale;
      }
      uint4 u0;
      u0.x = pack2bf(s0.x, s0.y); u0.y = pack2bf(s0.z, s0.w);
      u0.z = pack2bf(s1.x, s1.y); u0.w = pack2bf(s1.z, s1.w);
      *(uint4*)asw = u0;
      *(uint4*)bsw = rb0;
      *(uint4*)(bsw + 8) = rb1;
    }
    GEMM_FENCE_BARRIER();

    if (kt < 7) GEMM_ISSUE(kt + 1);

    short8 wf[4], vf[2];
#pragma unroll
    for (int ct = 0; ct < 4; ++ct)
      wf[ct] = *(const short8*)&Bs[(wc + ct * 16 + fr) * 40 + fg * 8];
#pragma unroll
    for (int rt2 = 0; rt2 < 2; ++rt2)
      vf[rt2] = *(const short8*)&As[(wr + rt2 * 16 + fr) * 40 + fg * 8];
#pragma unroll
    for (int ct = 0; ct < 4; ++ct)
#pragma unroll
      for (int rt2 = 0; rt2 < 2; ++rt2)
        acc[ct][rt2] = __builtin_amdgcn_mfma_f32_16x16x32_bf16(
            wf[ct], vf[rt2], acc[ct][rt2], 0, 0, 0);
  }
#undef GEMM_ISSUE
#undef GEMM_FENCE_BARRIER

  // Epilogue: D layout -> data row = fr, channel = fg*4 + reg
#pragma unroll
  for (int rt2 = 0; rt2 < 2; ++rt2) {
    const int m = m0 + wr + rt2 * 16 + fr;
    if (m >= M) continue;
#pragma unroll
    for (int ct = 0; ct < 4; ++ct) {
      const int ch = n0 + wc + ct * 16 + fg * 4;
      float o[4];
#pragma unroll
      for (int r = 0; r < 4; ++r) o[r] = acc[ct][rt2][r] + bias[ch + r];
      if (HAS_RES) {
        const float4 r4 = *(const float4*)&R[(size_t)m * N + ch];
        o[0] += r4.x; o[1] += r4.y; o[2] += r4.z; o[3] += r4.w;
      }
      if (BF16_OUT) {
        ushort4 u;
        u.x = f2bf(o[0]); u.y = f2bf(o[1]); u.z = f2bf(o[2]); u.w = f2bf(o[3]);
        *(ushort4*)((unsigned short*)Cv + (size_t)m * N + ch) = u;
      } else {
        float4 of; of.x = o[0]; of.y = o[1]; of.z = o[2]; of.w = o[3];
        *(float4*)((float*)Cv + (size_t)m * N + ch) = of;
      }
    }
  }
}

// ---------------------------------------------------------------------------
// Sampler v3: one block per (cam, query) pair; 256 threads = 2 sample-groups
// of 128 threads (2 channels each).
// ---------------------------------------------------------------------------
__global__ __launch_bounds__(256) void sampler3_kernel(
    const unsigned short* __restrict__ v, const float* __restrict__ offlog,
    const float* __restrict__ ref, const unsigned char* __restrict__ mask,
    float* __restrict__ slots) {
  const int pair = blockIdx.x;                 // c * NQ + q
  if (!mask[pair]) return;
  const int c = pair / NQ;
  const int q = pair - c * NQ;
  const int t = threadIdx.x;                   // 0..255

  __shared__ float sx[256], sy[256], sw[256];
  {
    const float Wl[4] = {160.f, 80.f, 40.f, 20.f};
    const float Hl[4] = {92.f, 46.f, 23.f, 12.f};
    const int combo = t;                       // (h,l,p): h=combo>>5
    const int l = (combo >> 3) & 3;
    const int p = combo & 7;
    const int z = p & 3;                       // NP//NZ x NZ reshape
    const float2 rz = ((const float2*)ref)[q * 4 + z];
    const float2 o2 = ((const float2*)offlog)[(size_t)q * 384 + combo];
    sx[combo] = rz.x * Wl[l] + o2.x - 0.5f;
    sy[combo] = rz.y * Hl[l] + o2.y - 0.5f;
    float lg = offlog[(size_t)q * 768 + 512 + combo];
    float mx = lg;
    for (int s = 16; s; s >>= 1) mx = fmaxf(mx, __shfl_xor(mx, s, 32));
    float e = __expf(lg - mx);
    float sm = e;
    for (int s = 16; s; s >>= 1) sm += __shfl_xor(sm, s, 32);
    sw[combo] = e / sm;
  }
  __syncthreads();

  const int WW[4] = {160, 80, 40, 20};
  const int HH[4] = {92, 46, 23, 12};
  const int LS[4] = {0, 14720, 18400, 19320};

  const int tt = t & 127;                      // channel pair
  const int grp = t >> 7;                      // sample group
  const unsigned int* vc =
      (const unsigned int*)(v + (size_t)c * (L_TOT * 256)) + tt;
  const int cbase = (tt >> 4) * 32;
  const int sbase = grp * 16;
  float acc0 = 0.f, acc1 = 0.f;

#pragma unroll
  for (int j = 0; j < 16; ++j) {
    const int s = sbase + j;
    const int lvl = s >> 3;
    const int combo = cbase + s;
    const float x = sx[combo], y = sy[combo], w = sw[combo];
    const float fx0 = floorf(x), fy0 = floorf(y);
    const float fx = x - fx0, fy = y - fy0;
    const int x0 = (int)fx0, y0 = (int)fy0;
    const int Wi = WW[lvl], Hi = HH[lvl];
    const int x0c = min(max(x0, 0), Wi - 1);
    const int x1c = min(max(x0 + 1, 0), Wi - 1);
    const int y0c = min(max(y0, 0), Hi - 1);
    const int y1c = min(max(y0 + 1, 0), Hi - 1);
    const float vx0 = (x0 >= 0 && x0 < Wi) ? 1.f : 0.f;
    const float vx1 = (x0 + 1 >= 0 && x0 + 1 < Wi) ? 1.f : 0.f;
    const float vy0 = (y0 >= 0 && y0 < Hi) ? 1.f : 0.f;
    const float vy1 = (y0 + 1 >= 0 && y0 + 1 < Hi) ? 1.f : 0.f;
    const unsigned int* vl = vc + (size_t)LS[lvl] * 128;
    const unsigned int u00 = vl[(y0c * Wi + x0c) * 128];
    const unsigned int u01 = vl[(y0c * Wi + x1c) * 128];
    const unsigned int u10 = vl[(y1c * Wi + x0c) * 128];
    const unsigned int u11 = vl[(y1c * Wi + x1c) * 128];
    const float w00 = (1.f - fx) * (1.f - fy) * vx0 * vy0 * w;
    const float w01 = fx * (1.f - fy) * vx1 * vy0 * w;
    const float w10 = (1.f - fx) * fy * vx0 * vy1 * w;
    const float w11 = fx * fy * vx1 * vy1 * w;
    acc0 += w00 * bf_lo(u00) + w01 * bf_lo(u01) +
            w10 * bf_lo(u10) + w11 * bf_lo(u11);
    acc1 += w00 * bf_hi(u00) + w01 * bf_hi(u01) +
            w10 * bf_hi(u10) + w11 * bf_hi(u11);
  }
  atomicAdd(&slots[q * 256 + tt * 2], acc0);
  atomicAdd(&slots[q * 256 + tt * 2 + 1], acc1);
}

// ---------------------------------------------------------------------------
extern "C" void kernel_launch(void* const* d_in, const int* in_sizes, int n_in,
                              void* d_out, int out_size, void* d_ws,
                              size_t ws_size, hipStream_t stream) {
  const float* query  = (const float*)d_in[0];
  // d_in[1] = key : unused by the reference forward
  const float* value  = (const float*)d_in[2];
  const float* qpos   = (const float*)d_in[3];
  const float* refpts = (const float*)d_in[4];
  const void*  bmask  = d_in[5];
  const float* W_value = (const float*)d_in[8];
  const float* b_value = (const float*)d_in[9];
  const float* W_off   = (const float*)d_in[10];
  const float* b_off   = (const float*)d_in[11];
  const float* W_attn  = (const float*)d_in[12];
  const float* b_attn  = (const float*)d_in[13];
  const float* W_out   = (const float*)d_in[14];
  const float* b_out   = (const float*)d_in[15];
  float* out = (float*)d_out;

  // workspace layout (~71 MB)
  unsigned short* ws_v = (unsigned short*)d_ws;                    // M_VAL*256 bf16
  unsigned short* ws_wv   = ws_v + (size_t)M_VAL * 256;            // 65536
  unsigned short* ws_wq   = ws_wv + 65536;                         // 196608
  unsigned short* ws_wout = ws_wq + 196608;                        // 65536
  float* ws_offlog = (float*)(ws_wout + 65536);                    // NQ*768
  float* ws_slots  = ws_offlog + (size_t)NQ * 768;                 // NQ*256
  float* ws_invcnt = ws_slots + (size_t)NQ * 256;                  // NQ
  float* ws_bcat   = ws_invcnt + NQ;                               // 768
  unsigned char* ws_mask = (unsigned char*)(ws_bcat + 768);        // NCAMS*NQ

  canon_mask_kernel<<<60, 256, 0, stream>>>(bmask, ws_mask, ws_invcnt,
                                            b_off, b_attn, ws_bcat, ws_slots);
  cvt_weights_kernel<<<1280, 256, 0, stream>>>(
      W_value, W_off, W_attn, W_out, ws_wv, ws_wq, ws_wout);

  // v = value @ W_value^T + b_value   (117360 x 256), bf16 out — async LDS
  vgemm_async_kernel<<<dim3(1834, 2), 256, 0, stream>>>(
      value, ws_wv, b_value, ws_v, M_VAL);

  // [off | logits] = (q+qpos) @ [W_off;W_attn]^T + bcat   (2500 x 768)
  gemm_mfma_kernel<false, true, false, false><<<dim3(40, 6), 256, 0, stream>>>(
      query, qpos, ws_wq, ws_bcat, nullptr, nullptr, (void*)ws_offlog,
      NQ, 768);

  sampler3_kernel<<<NCAMS * NQ, 256, 0, stream>>>(
      ws_v, ws_offlog, refpts, ws_mask, ws_slots);

  // out = (slots/cnt) @ W_out^T + b_out + query   (2500 x 256)
  gemm_mfma_kernel<false, false, true, true><<<dim3(40, 2), 256, 0, stream>>>(
      ws_slots, nullptr, ws_wout, b_out, query, ws_invcnt, (void*)out,
      NQ, 256);
}